// Round 13
// baseline (92.801 us; speedup 1.0000x reference)
//
#include <hip/hip_runtime.h>

#define LL 64
#define NN 20
#define DTC 0.01f
#define NOISEC 1e-3f
#define LN2C 0.69314718056f

typedef __attribute__((ext_vector_type(8))) short short8x;
typedef __attribute__((ext_vector_type(4))) float f32x4;
typedef __attribute__((ext_vector_type(4))) int v4i;

// pack two floats to bf16x2 with round-to-nearest-even (manual, no HIP types)
__device__ __forceinline__ unsigned bf16r(float x) {
    union { float f; unsigned u; } a; a.f = x;
    return (a.u + (0x7fffu + ((a.u >> 16) & 1u))) >> 16;
}
__device__ __forceinline__ unsigned pk_bf16(float x, float y) {
    return bf16r(x) | (bf16r(y) << 16);
}

// B-fragment lane-shift: Bv[d+1](nh,qd) = Bv[d](nh-1,qd), 0 at nh==0.
// Exactly v_mov_dpp row_shr:1 (16-lane rows) with bound_ctrl zero-fill.
__device__ __forceinline__ short8x dpp_shr1(short8x v) {
    v4i p = __builtin_bit_cast(v4i, v);
    v4i q;
    q.x = __builtin_amdgcn_update_dpp(0, p.x, 0x111, 0xf, 0xf, true);
    q.y = __builtin_amdgcn_update_dpp(0, p.y, 0x111, 0xf, 0xf, true);
    q.z = __builtin_amdgcn_update_dpp(0, p.z, 0x111, 0xf, 0xf, true);
    q.w = __builtin_amdgcn_update_dpp(0, p.w, 0x111, 0xf, 0xf, true);
    return __builtin_bit_cast(short8x, q);
}

// One wave (64 thr) per channel c = b*64+l. NO barriers anywhere (per-wave
// in-order DS ordering carries all write->read deps).
// Block-Toeplitz MFMA (validated R8/R9/R12): Qn[32I+i] = sum_d sum_k
// G_d[i][k]*Qsrc[32(I-d)+k], G_d[i][k] = g(32d+i-k), g = DT*q_n reversed,
// zero for negative arg. gt copy kk pos w holds r[w+kk] so every A-read is
// one aligned ds_read_b128; Q zero-prefix handles the B boundary.
// R12: B-fragments for d>=1 via DPP row_shr:1 chain (off the LDS pipe).
// R13: cross-step prefetch — A(n+1) reloaded into the SAME (dead) register
// arrays and B(n+1) read in the step-n epilogue, after fill_g(n+1)/Q-write
// (in-order DS makes both safe); their latency hides under step n+1's
// DPP+MFMA chain instead of stalling its start.
__global__ __launch_bounds__(64, 1) void outage_kernel(
    const float* __restrict__ pathloss,
    const float* __restrict__ powers,
    float* __restrict__ out)
{
    __shared__ __align__(16) unsigned short gt[2][8][544];  // 8 shifted copies, ping-pong
    __shared__ __align__(16) unsigned short Qb[2][1024];    // [0,512)=zeros, [512,1024)=data

    const int lane = threadIdx.x;
    const int c = blockIdx.x, b = c >> 6, l = c & 63;
    const int nh = lane & 15;          // MFMA m / n index
    const int qd = lane >> 4;          // MFMA quad (k-group)

    // ---- inline prep: rowsum + diag of pathloss row l (coalesced) ----
    const float pl = pathloss[l * LL + lane];
    float rs = pl;
    #pragma unroll
    for (int mk = 1; mk < 64; mk <<= 1) rs += __shfl_xor(rs, mk, 64);
    const float dg   = __shfl(pl, l, 64);
    const float dsum = rs - dg;

    // per-lane time constants, tau = 8*lane + u
    float P2[8], P1[8];
    #pragma unroll
    for (int u = 0; u < 8; ++u) {
        P2[u] = exp2f((8 * lane + u) * DTC);
        P1[u] = P2[u] - 1.f;
    }

    // zero Q prefixes (1 KiB each) and gt tails [512,544) of both buffers
    *((uint4*)&Qb[0][0] + lane) = uint4{0u, 0u, 0u, 0u};
    *((uint4*)&Qb[1][0] + lane) = uint4{0u, 0u, 0u, 0u};
    {
        const int bb = lane >> 5, w = lane & 31;
        #pragma unroll
        for (int k = 0; k < 8; ++k) gt[bb][k][512 + w] = 0;
    }

    // Q0(tau) = 1 - exp(-(2^{tau*DT}-1)*s0), bf16 into Qb[0]
    const float p0 = powers[(b * NN + 0) * LL + l];
    const float s0 = dg * p0 / (p0 * dsum + NOISEC);
    float q7;
    {
        float v[8];
        #pragma unroll
        for (int u = 0; u < 8; ++u) v[u] = 1.f - expf(-P1[u] * s0);
        q7 = v[7];                                  // lane 63: Q0[511]
        uint4 d4 = { pk_bf16(v[0], v[1]), pk_bf16(v[2], v[3]),
                     pk_bf16(v[4], v[5]), pk_bf16(v[6], v[7]) };
        *(uint4*)&Qb[0][512 + 8 * lane] = d4;
    }

    const float p1v = powers[(b * NN + 1) * LL + l];
    float lossCh = 1.f + p0 + (p1v + 1.f) * q7;     // only lane 63's is used

    // fill the 8 shifted copies of r[tau] = DT*q_n(tau) for a step into buf
    auto fill_g = [&](int buf, float p) {
        float s  = dg * p / (p * dsum + NOISEC);
        float cm = s * LN2C * DTC;
        unsigned F[8];                               // F[0..3] own pairs, F[4..7] neighbor
        #pragma unroll
        for (int w = 0; w < 4; ++w) {
            float a  = expf(-P1[2 * w] * s) * P2[2 * w] * cm;
            float bb = expf(-P1[2 * w + 1] * s) * P2[2 * w + 1] * cm;
            F[w] = pk_bf16(a, bb);
        }
        #pragma unroll
        for (int w = 0; w < 4; ++w) {
            unsigned t = (unsigned)__shfl_down((int)F[w], 1, 64);
            F[4 + w] = (lane == 63) ? 0u : t;       // tau >= 512 -> 0
        }
        unsigned E[7];                               // odd-phase pairs
        #pragma unroll
        for (int j = 0; j < 7; ++j) E[j] = (F[j] >> 16) | (F[j + 1] << 16);
        #pragma unroll
        for (int k = 0; k < 8; ++k) {               // copy k pos 8L+w holds r[8L+w+k]
            uint4 d4;
            if ((k & 1) == 0) d4 = uint4{F[k / 2], F[k / 2 + 1], F[k / 2 + 2], F[k / 2 + 3]};
            else              d4 = uint4{E[k / 2], E[k / 2 + 1], E[k / 2 + 2], E[k / 2 + 3]};
            *(uint4*)&gt[buf][k][8 * lane] = d4;
        }
    };
    fill_g(1, p1v);                                 // g-table for step n=1

    const int kk    = (7 - nh) & 7;                 // this lane's copy index
    const int baseA = 511 - nh + 8 * qd - kk;       // == 0 mod 8 (16B aligned)
    const int baseB = 512 + 32 * nh + 8 * qd;
    const int dstw  = 512 + 32 * nh + 4 * qd;       // +16 for M-tile 1

    float pnext = powers[(b * NN + 2) * LL + l];    // pw[n+1] entering n=1

    // initial prefetch for step 1 (in-order DS: after fill_g(1) + Q0 writes)
    short8x A0v[16], A1v[16], Bcur;
    {
        const unsigned short* pg1 = &gt[1][kk][0];
        #pragma unroll
        for (int d = 0; d < 16; ++d) {
            A0v[d] = *(const short8x*)&pg1[baseA - 32 * d];
            A1v[d] = *(const short8x*)&pg1[baseA - 32 * d - 16];
        }
        Bcur = *(const short8x*)&Qb[0][baseB];
    }

    for (int n = 1; n < NN; ++n) {
        unsigned short* pdst = &Qb[n & 1][0];

        // issue next-next power load early (lands during this step's work)
        float pfut = 0.f;
        if (n <= NN - 3) pfut = powers[(b * NN + n + 2) * LL + l];

        // ---- B: DPP row_shr:1 chain from the prefetched Bcur ----
        short8x Bv[16];
        Bv[0] = Bcur;
        #pragma unroll
        for (int d = 1; d < 16; ++d) Bv[d] = dpp_shr1(Bv[d - 1]);

        // ---- fill g-table for step n+1 (other gt buffer) ----
        if (n < NN - 1) fill_g((n + 1) & 1, pnext);

        // ---- 4 independent MFMA chains, consuming prefetched A0v/A1v ----
        f32x4 acc0a = {0.f, 0.f, 0.f, 0.f}, acc0b = {0.f, 0.f, 0.f, 0.f};
        f32x4 acc1a = {0.f, 0.f, 0.f, 0.f}, acc1b = {0.f, 0.f, 0.f, 0.f};
        #pragma unroll
        for (int d = 0; d < 16; d += 2) {
            acc0a = __builtin_amdgcn_mfma_f32_16x16x32_bf16(A0v[d],     Bv[d],     acc0a, 0, 0, 0);
            acc1a = __builtin_amdgcn_mfma_f32_16x16x32_bf16(A1v[d],     Bv[d],     acc1a, 0, 0, 0);
            acc0b = __builtin_amdgcn_mfma_f32_16x16x32_bf16(A0v[d + 1], Bv[d + 1], acc0b, 0, 0, 0);
            acc1b = __builtin_amdgcn_mfma_f32_16x16x32_bf16(A1v[d + 1], Bv[d + 1], acc1b, 0, 0, 0);
        }
        f32x4 acc0 = acc0a + acc0b;
        f32x4 acc1 = acc1a + acc1b;

        // write Qn (bf16): lane holds rows 4qd..4qd+3 of both M-tiles, col nh
        *(uint2*)&pdst[dstw]      = uint2{pk_bf16(acc0.x, acc0.y), pk_bf16(acc0.z, acc0.w)};
        *(uint2*)&pdst[dstw + 16] = uint2{pk_bf16(acc1.x, acc1.y), pk_bf16(acc1.z, acc1.w)};

        // ---- epilogue prefetch for step n+1 (A regs are dead post-MFMA;
        //      in-order DS: fill_g(n+1) writes precede these reads, and the
        //      Q-writes above precede the Bcur read) ----
        if (n < NN - 1) {
            const unsigned short* pgn = &gt[(n + 1) & 1][kk][0];
            #pragma unroll
            for (int d = 0; d < 16; ++d) {
                A0v[d] = *(const short8x*)&pgn[baseA - 32 * d];
                A1v[d] = *(const short8x*)&pgn[baseA - 32 * d - 16];
            }
            Bcur = *(const short8x*)&pdst[baseB];
        }

        // loss tap: lane 63 acc1.w == Qn[511] (row 31, col 15), fp32 precision
        float wgt = (n < NN - 1) ? (pnext + 1.f) : 1.f;   // pnext == pw[n+1]
        lossCh += wgt * acc1.w;
        pnext = pfut;
    }

    if (lane == 63) atomicAdd(out, lossCh);
}

extern "C" void kernel_launch(void* const* d_in, const int* in_sizes, int n_in,
                              void* d_out, int out_size, void* d_ws, size_t ws_size,
                              hipStream_t stream) {
    const float* pathloss = (const float*)d_in[0];
    const float* powers   = (const float*)d_in[1];
    float* outp = (float*)d_out;

    (void)hipMemsetAsync(d_out, 0, sizeof(float) * out_size, stream);
    outage_kernel<<<16 * LL, 64, 0, stream>>>(pathloss, powers, outp);
}

// Round 14
// 90.949 us; speedup vs baseline: 1.0204x; 1.0204x over previous
//
#include <hip/hip_runtime.h>

#define LL 64
#define NN 20
#define DTC 0.01f
#define NOISEC 1e-3f
#define LN2C 0.69314718056f

typedef __attribute__((ext_vector_type(8))) short short8x;
typedef __attribute__((ext_vector_type(4))) float f32x4;
typedef __attribute__((ext_vector_type(4))) int v4i;

// pack two floats to bf16x2 with round-to-nearest-even (manual, no HIP types)
__device__ __forceinline__ unsigned bf16r(float x) {
    union { float f; unsigned u; } a; a.f = x;
    return (a.u + (0x7fffu + ((a.u >> 16) & 1u))) >> 16;
}
__device__ __forceinline__ unsigned pk_bf16(float x, float y) {
    return bf16r(x) | (bf16r(y) << 16);
}

// B-fragment lane-shift: Bv[d+1](nh,qd) = Bv[d](nh-1,qd), 0 at nh==0.
// Exactly v_mov_dpp row_shr:1 (16-lane rows) with bound_ctrl zero-fill.
__device__ __forceinline__ short8x dpp_shr1(short8x v) {
    v4i p = __builtin_bit_cast(v4i, v);
    v4i q;
    q.x = __builtin_amdgcn_update_dpp(0, p.x, 0x111, 0xf, 0xf, true);
    q.y = __builtin_amdgcn_update_dpp(0, p.y, 0x111, 0xf, 0xf, true);
    q.z = __builtin_amdgcn_update_dpp(0, p.z, 0x111, 0xf, 0xf, true);
    q.w = __builtin_amdgcn_update_dpp(0, p.w, 0x111, 0xf, 0xf, true);
    return __builtin_bit_cast(short8x, q);
}

// One wave (64 thr) per channel c = b*64+l. NO barriers anywhere (per-wave
// in-order DS ordering carries all write->read deps).
// Block-Toeplitz MFMA (validated R8/R9/R12): Qn[32I+i] = sum_d sum_k
// G_d[i][k]*Qsrc[32(I-d)+k], G_d[i][k] = g(32d+i-k), g = DT*q_n reversed,
// zero for negative arg. gt copy kk pos w holds r[w+kk] so every A-read is
// one aligned ds_read_b128; Q zero-prefix handles the B boundary.
// R12 (best measured, 88.7 us wall): B-fragments for d>=1 derived from Bv[0]
// via DPP row_shr:1 chains (VALU) instead of 15 ds_read_b128.
// R13's epilogue A-prefetch was compiler-defeated (VGPR stayed 120) and
// regressed; reverted.
__global__ __launch_bounds__(64, 1) void outage_kernel(
    const float* __restrict__ pathloss,
    const float* __restrict__ powers,
    float* __restrict__ out)
{
    __shared__ __align__(16) unsigned short gt[2][8][544];  // 8 shifted copies, ping-pong
    __shared__ __align__(16) unsigned short Qb[2][1024];    // [0,512)=zeros, [512,1024)=data

    const int lane = threadIdx.x;
    const int c = blockIdx.x, b = c >> 6, l = c & 63;
    const int nh = lane & 15;          // MFMA m / n index
    const int qd = lane >> 4;          // MFMA quad (k-group)

    // ---- inline prep: rowsum + diag of pathloss row l (coalesced) ----
    const float pl = pathloss[l * LL + lane];
    float rs = pl;
    #pragma unroll
    for (int mk = 1; mk < 64; mk <<= 1) rs += __shfl_xor(rs, mk, 64);
    const float dg   = __shfl(pl, l, 64);
    const float dsum = rs - dg;

    // per-lane time constants, tau = 8*lane + u
    float P2[8], P1[8];
    #pragma unroll
    for (int u = 0; u < 8; ++u) {
        P2[u] = exp2f((8 * lane + u) * DTC);
        P1[u] = P2[u] - 1.f;
    }

    // zero Q prefixes (1 KiB each) and gt tails [512,544) of both buffers
    *((uint4*)&Qb[0][0] + lane) = uint4{0u, 0u, 0u, 0u};
    *((uint4*)&Qb[1][0] + lane) = uint4{0u, 0u, 0u, 0u};
    {
        const int bb = lane >> 5, w = lane & 31;
        #pragma unroll
        for (int k = 0; k < 8; ++k) gt[bb][k][512 + w] = 0;
    }

    // Q0(tau) = 1 - exp(-(2^{tau*DT}-1)*s0), bf16 into Qb[0]
    const float p0 = powers[(b * NN + 0) * LL + l];
    const float s0 = dg * p0 / (p0 * dsum + NOISEC);
    float q7;
    {
        float v[8];
        #pragma unroll
        for (int u = 0; u < 8; ++u) v[u] = 1.f - expf(-P1[u] * s0);
        q7 = v[7];                                  // lane 63: Q0[511]
        uint4 d4 = { pk_bf16(v[0], v[1]), pk_bf16(v[2], v[3]),
                     pk_bf16(v[4], v[5]), pk_bf16(v[6], v[7]) };
        *(uint4*)&Qb[0][512 + 8 * lane] = d4;
    }

    const float p1v = powers[(b * NN + 1) * LL + l];
    float lossCh = 1.f + p0 + (p1v + 1.f) * q7;     // only lane 63's is used

    // fill the 8 shifted copies of r[tau] = DT*q_n(tau) for a step into buf
    auto fill_g = [&](int buf, float p) {
        float s  = dg * p / (p * dsum + NOISEC);
        float cm = s * LN2C * DTC;
        unsigned F[8];                               // F[0..3] own pairs, F[4..7] neighbor
        #pragma unroll
        for (int w = 0; w < 4; ++w) {
            float a  = expf(-P1[2 * w] * s) * P2[2 * w] * cm;
            float bb = expf(-P1[2 * w + 1] * s) * P2[2 * w + 1] * cm;
            F[w] = pk_bf16(a, bb);
        }
        #pragma unroll
        for (int w = 0; w < 4; ++w) {
            unsigned t = (unsigned)__shfl_down((int)F[w], 1, 64);
            F[4 + w] = (lane == 63) ? 0u : t;       // tau >= 512 -> 0
        }
        unsigned E[7];                               // odd-phase pairs
        #pragma unroll
        for (int j = 0; j < 7; ++j) E[j] = (F[j] >> 16) | (F[j + 1] << 16);
        #pragma unroll
        for (int k = 0; k < 8; ++k) {               // copy k pos 8L+w holds r[8L+w+k]
            uint4 d4;
            if ((k & 1) == 0) d4 = uint4{F[k / 2], F[k / 2 + 1], F[k / 2 + 2], F[k / 2 + 3]};
            else              d4 = uint4{E[k / 2], E[k / 2 + 1], E[k / 2 + 2], E[k / 2 + 3]};
            *(uint4*)&gt[buf][k][8 * lane] = d4;
        }
    };
    fill_g(1, p1v);                                 // g-table for step n=1

    const int kk    = (7 - nh) & 7;                 // this lane's copy index
    const int baseA = 511 - nh + 8 * qd - kk;       // == 0 mod 8 (16B aligned)
    const int baseB = 512 + 32 * nh + 8 * qd;
    const int dstw  = 512 + 32 * nh + 4 * qd;       // +16 for M-tile 1

    float pnext = powers[(b * NN + 2) * LL + l];    // pw[n+1] entering n=1

    for (int n = 1; n < NN; ++n) {
        const unsigned short* psrc = &Qb[(n + 1) & 1][0];   // == (n-1)&1
        const unsigned short* pg   = &gt[n & 1][kk][0];
        unsigned short* pdst       = &Qb[n & 1][0];

        // issue next-next power load early (lands during this step's work)
        float pfut = 0.f;
        if (n <= NN - 3) pfut = powers[(b * NN + n + 2) * LL + l];

        // ---- B: one ds_read_b128 (d=0) + DPP row_shr:1 chain for d>=1 ----
        short8x Bv[16];
        Bv[0] = *(const short8x*)&psrc[baseB];
        #pragma unroll
        for (int d = 1; d < 16; ++d) Bv[d] = dpp_shr1(Bv[d - 1]);

        // ---- A operands for this step (32 x ds_read_b128) ----
        short8x A0v[16], A1v[16];
        #pragma unroll
        for (int d = 0; d < 16; ++d) {
            A0v[d] = *(const short8x*)&pg[baseA - 32 * d];
            A1v[d] = *(const short8x*)&pg[baseA - 32 * d - 16];
        }

        // ---- fill g-table for step n+1 (independent buffer) under the
        //      MFMA shadow; uses pnext loaded one iteration ago ----
        if (n < NN - 1) fill_g((n + 1) & 1, pnext);

        // ---- 4 independent MFMA chains (d even/odd x 2 M-tiles) ----
        f32x4 acc0a = {0.f, 0.f, 0.f, 0.f}, acc0b = {0.f, 0.f, 0.f, 0.f};
        f32x4 acc1a = {0.f, 0.f, 0.f, 0.f}, acc1b = {0.f, 0.f, 0.f, 0.f};
        #pragma unroll
        for (int d = 0; d < 16; d += 2) {
            acc0a = __builtin_amdgcn_mfma_f32_16x16x32_bf16(A0v[d],     Bv[d],     acc0a, 0, 0, 0);
            acc1a = __builtin_amdgcn_mfma_f32_16x16x32_bf16(A1v[d],     Bv[d],     acc1a, 0, 0, 0);
            acc0b = __builtin_amdgcn_mfma_f32_16x16x32_bf16(A0v[d + 1], Bv[d + 1], acc0b, 0, 0, 0);
            acc1b = __builtin_amdgcn_mfma_f32_16x16x32_bf16(A1v[d + 1], Bv[d + 1], acc1b, 0, 0, 0);
        }
        f32x4 acc0 = acc0a + acc0b;
        f32x4 acc1 = acc1a + acc1b;

        // write Qn (bf16): lane holds rows 4qd..4qd+3 of both M-tiles, col nh
        *(uint2*)&pdst[dstw]      = uint2{pk_bf16(acc0.x, acc0.y), pk_bf16(acc0.z, acc0.w)};
        *(uint2*)&pdst[dstw + 16] = uint2{pk_bf16(acc1.x, acc1.y), pk_bf16(acc1.z, acc1.w)};

        // loss tap: lane 63 acc1.w == Qn[511] (row 31, col 15), fp32 precision
        float wgt = (n < NN - 1) ? (pnext + 1.f) : 1.f;   // pnext == pw[n+1]
        lossCh += wgt * acc1.w;
        pnext = pfut;
    }

    if (lane == 63) atomicAdd(out, lossCh);
}

extern "C" void kernel_launch(void* const* d_in, const int* in_sizes, int n_in,
                              void* d_out, int out_size, void* d_ws, size_t ws_size,
                              hipStream_t stream) {
    const float* pathloss = (const float*)d_in[0];
    const float* powers   = (const float*)d_in[1];
    float* outp = (float*)d_out;

    (void)hipMemsetAsync(d_out, 0, sizeof(float) * out_size, stream);
    outage_kernel<<<16 * LL, 64, 0, stream>>>(pathloss, powers, outp);
}

// Round 15
// 89.671 us; speedup vs baseline: 1.0349x; 1.0143x over previous
//
#include <hip/hip_runtime.h>

#define LL 64
#define NN 20
#define DTC 0.01f
#define NOISEC 1e-3f
#define LN2C 0.69314718056f

typedef __attribute__((ext_vector_type(8))) short short8x;
typedef __attribute__((ext_vector_type(4))) float f32x4;
typedef __attribute__((ext_vector_type(4))) int v4i;

// pack two floats to bf16x2 with round-to-nearest-even (manual, no HIP types)
__device__ __forceinline__ unsigned bf16r(float x) {
    union { float f; unsigned u; } a; a.f = x;
    return (a.u + (0x7fffu + ((a.u >> 16) & 1u))) >> 16;
}
__device__ __forceinline__ unsigned pk_bf16(float x, float y) {
    return bf16r(x) | (bf16r(y) << 16);
}

// B-fragment lane-shift by D rows: Bv[D](nh,qd) = Bv[0](nh-D,qd), 0 at nh<D.
// v_mov_dpp row_shr:D (16-lane rows) with bound_ctrl zero-fill — all 15
// shifts derived INDEPENDENTLY from Bv[0] (depth-1, no dependent chain).
template<int D>
__device__ __forceinline__ short8x dpp_shrD(short8x v) {
    v4i p = __builtin_bit_cast(v4i, v);
    v4i q;
    q.x = __builtin_amdgcn_update_dpp(0, p.x, 0x110 + D, 0xf, 0xf, true);
    q.y = __builtin_amdgcn_update_dpp(0, p.y, 0x110 + D, 0xf, 0xf, true);
    q.z = __builtin_amdgcn_update_dpp(0, p.z, 0x110 + D, 0xf, 0xf, true);
    q.w = __builtin_amdgcn_update_dpp(0, p.w, 0x110 + D, 0xf, 0xf, true);
    return __builtin_bit_cast(short8x, q);
}

// One wave (64 thr) per channel c = b*64+l. NO barriers anywhere (per-wave
// in-order DS ordering carries all write->read deps).
// Block-Toeplitz MFMA (validated R8/R9/R12): Qn[32I+i] = sum_d sum_k
// G_d[i][k]*Qsrc[32(I-d)+k], G_d[i][k] = g(32d+i-k), g = DT*q_n reversed,
// zero for negative arg. gt copy kk pos w holds r[w+kk] so every A-read is
// one aligned ds_read_b128; Q zero-prefix handles the B boundary.
// R12: B-fragments for d>=1 via DPP (off the LDS pipe).
// R15: DPP shifts flattened to independent row_shr:d from Bv[0] (kills the
// 15-deep dependent mov chain on the step critical path).
__global__ __launch_bounds__(64, 1) void outage_kernel(
    const float* __restrict__ pathloss,
    const float* __restrict__ powers,
    float* __restrict__ out)
{
    __shared__ __align__(16) unsigned short gt[2][8][544];  // 8 shifted copies, ping-pong
    __shared__ __align__(16) unsigned short Qb[2][1024];    // [0,512)=zeros, [512,1024)=data

    const int lane = threadIdx.x;
    const int c = blockIdx.x, b = c >> 6, l = c & 63;
    const int nh = lane & 15;          // MFMA m / n index
    const int qd = lane >> 4;          // MFMA quad (k-group)

    // ---- inline prep: rowsum + diag of pathloss row l (coalesced) ----
    const float pl = pathloss[l * LL + lane];
    float rs = pl;
    #pragma unroll
    for (int mk = 1; mk < 64; mk <<= 1) rs += __shfl_xor(rs, mk, 64);
    const float dg   = __shfl(pl, l, 64);
    const float dsum = rs - dg;

    // per-lane time constants, tau = 8*lane + u
    float P2[8], P1[8];
    #pragma unroll
    for (int u = 0; u < 8; ++u) {
        P2[u] = exp2f((8 * lane + u) * DTC);
        P1[u] = P2[u] - 1.f;
    }

    // zero Q prefixes (1 KiB each) and gt tails [512,544) of both buffers
    *((uint4*)&Qb[0][0] + lane) = uint4{0u, 0u, 0u, 0u};
    *((uint4*)&Qb[1][0] + lane) = uint4{0u, 0u, 0u, 0u};
    {
        const int bb = lane >> 5, w = lane & 31;
        #pragma unroll
        for (int k = 0; k < 8; ++k) gt[bb][k][512 + w] = 0;
    }

    // Q0(tau) = 1 - exp(-(2^{tau*DT}-1)*s0), bf16 into Qb[0]
    const float p0 = powers[(b * NN + 0) * LL + l];
    const float s0 = dg * p0 / (p0 * dsum + NOISEC);
    float q7;
    {
        float v[8];
        #pragma unroll
        for (int u = 0; u < 8; ++u) v[u] = 1.f - expf(-P1[u] * s0);
        q7 = v[7];                                  // lane 63: Q0[511]
        uint4 d4 = { pk_bf16(v[0], v[1]), pk_bf16(v[2], v[3]),
                     pk_bf16(v[4], v[5]), pk_bf16(v[6], v[7]) };
        *(uint4*)&Qb[0][512 + 8 * lane] = d4;
    }

    const float p1v = powers[(b * NN + 1) * LL + l];
    float lossCh = 1.f + p0 + (p1v + 1.f) * q7;     // only lane 63's is used

    // fill the 8 shifted copies of r[tau] = DT*q_n(tau) for a step into buf
    auto fill_g = [&](int buf, float p) {
        float s  = dg * p / (p * dsum + NOISEC);
        float cm = s * LN2C * DTC;
        unsigned F[8];                               // F[0..3] own pairs, F[4..7] neighbor
        #pragma unroll
        for (int w = 0; w < 4; ++w) {
            float a  = expf(-P1[2 * w] * s) * P2[2 * w] * cm;
            float bb = expf(-P1[2 * w + 1] * s) * P2[2 * w + 1] * cm;
            F[w] = pk_bf16(a, bb);
        }
        #pragma unroll
        for (int w = 0; w < 4; ++w) {
            unsigned t = (unsigned)__shfl_down((int)F[w], 1, 64);
            F[4 + w] = (lane == 63) ? 0u : t;       // tau >= 512 -> 0
        }
        unsigned E[7];                               // odd-phase pairs
        #pragma unroll
        for (int j = 0; j < 7; ++j) E[j] = (F[j] >> 16) | (F[j + 1] << 16);
        #pragma unroll
        for (int k = 0; k < 8; ++k) {               // copy k pos 8L+w holds r[8L+w+k]
            uint4 d4;
            if ((k & 1) == 0) d4 = uint4{F[k / 2], F[k / 2 + 1], F[k / 2 + 2], F[k / 2 + 3]};
            else              d4 = uint4{E[k / 2], E[k / 2 + 1], E[k / 2 + 2], E[k / 2 + 3]};
            *(uint4*)&gt[buf][k][8 * lane] = d4;
        }
    };
    fill_g(1, p1v);                                 // g-table for step n=1

    const int kk    = (7 - nh) & 7;                 // this lane's copy index
    const int baseA = 511 - nh + 8 * qd - kk;       // == 0 mod 8 (16B aligned)
    const int baseB = 512 + 32 * nh + 8 * qd;
    const int dstw  = 512 + 32 * nh + 4 * qd;       // +16 for M-tile 1

    float pnext = powers[(b * NN + 2) * LL + l];    // pw[n+1] entering n=1

    for (int n = 1; n < NN; ++n) {
        const unsigned short* psrc = &Qb[(n + 1) & 1][0];   // == (n-1)&1
        const unsigned short* pg   = &gt[n & 1][kk][0];
        unsigned short* pdst       = &Qb[n & 1][0];

        // issue next-next power load early (lands during this step's work)
        float pfut = 0.f;
        if (n <= NN - 3) pfut = powers[(b * NN + n + 2) * LL + l];

        // ---- B: one ds_read_b128 (d=0) + 15 INDEPENDENT row_shr:d DPPs ----
        short8x Bv[16];
        Bv[0]  = *(const short8x*)&psrc[baseB];
        Bv[1]  = dpp_shrD<1>(Bv[0]);
        Bv[2]  = dpp_shrD<2>(Bv[0]);
        Bv[3]  = dpp_shrD<3>(Bv[0]);
        Bv[4]  = dpp_shrD<4>(Bv[0]);
        Bv[5]  = dpp_shrD<5>(Bv[0]);
        Bv[6]  = dpp_shrD<6>(Bv[0]);
        Bv[7]  = dpp_shrD<7>(Bv[0]);
        Bv[8]  = dpp_shrD<8>(Bv[0]);
        Bv[9]  = dpp_shrD<9>(Bv[0]);
        Bv[10] = dpp_shrD<10>(Bv[0]);
        Bv[11] = dpp_shrD<11>(Bv[0]);
        Bv[12] = dpp_shrD<12>(Bv[0]);
        Bv[13] = dpp_shrD<13>(Bv[0]);
        Bv[14] = dpp_shrD<14>(Bv[0]);
        Bv[15] = dpp_shrD<15>(Bv[0]);

        // ---- A operands for this step (32 x ds_read_b128) ----
        short8x A0v[16], A1v[16];
        #pragma unroll
        for (int d = 0; d < 16; ++d) {
            A0v[d] = *(const short8x*)&pg[baseA - 32 * d];
            A1v[d] = *(const short8x*)&pg[baseA - 32 * d - 16];
        }

        // ---- fill g-table for step n+1 (independent buffer) under the
        //      MFMA shadow; uses pnext loaded one iteration ago ----
        if (n < NN - 1) fill_g((n + 1) & 1, pnext);

        // ---- 4 independent MFMA chains (d even/odd x 2 M-tiles) ----
        f32x4 acc0a = {0.f, 0.f, 0.f, 0.f}, acc0b = {0.f, 0.f, 0.f, 0.f};
        f32x4 acc1a = {0.f, 0.f, 0.f, 0.f}, acc1b = {0.f, 0.f, 0.f, 0.f};
        #pragma unroll
        for (int d = 0; d < 16; d += 2) {
            acc0a = __builtin_amdgcn_mfma_f32_16x16x32_bf16(A0v[d],     Bv[d],     acc0a, 0, 0, 0);
            acc1a = __builtin_amdgcn_mfma_f32_16x16x32_bf16(A1v[d],     Bv[d],     acc1a, 0, 0, 0);
            acc0b = __builtin_amdgcn_mfma_f32_16x16x32_bf16(A0v[d + 1], Bv[d + 1], acc0b, 0, 0, 0);
            acc1b = __builtin_amdgcn_mfma_f32_16x16x32_bf16(A1v[d + 1], Bv[d + 1], acc1b, 0, 0, 0);
        }
        f32x4 acc0 = acc0a + acc0b;
        f32x4 acc1 = acc1a + acc1b;

        // write Qn (bf16): lane holds rows 4qd..4qd+3 of both M-tiles, col nh
        *(uint2*)&pdst[dstw]      = uint2{pk_bf16(acc0.x, acc0.y), pk_bf16(acc0.z, acc0.w)};
        *(uint2*)&pdst[dstw + 16] = uint2{pk_bf16(acc1.x, acc1.y), pk_bf16(acc1.z, acc1.w)};

        // loss tap: lane 63 acc1.w == Qn[511] (row 31, col 15), fp32 precision
        float wgt = (n < NN - 1) ? (pnext + 1.f) : 1.f;   // pnext == pw[n+1]
        lossCh += wgt * acc1.w;
        pnext = pfut;
    }

    if (lane == 63) atomicAdd(out, lossCh);
}

extern "C" void kernel_launch(void* const* d_in, const int* in_sizes, int n_in,
                              void* d_out, int out_size, void* d_ws, size_t ws_size,
                              hipStream_t stream) {
    const float* pathloss = (const float*)d_in[0];
    const float* powers   = (const float*)d_in[1];
    float* outp = (float*)d_out;

    (void)hipMemsetAsync(d_out, 0, sizeof(float) * out_size, stream);
    outage_kernel<<<16 * LL, 64, 0, stream>>>(pathloss, powers, outp);
}